// Round 2
// baseline (4422.156 us; speedup 1.0000x reference)
//
#include <hip/hip_runtime.h>
#include <stdint.h>

// WindowAttention1D, FULL FP32 pipeline (threshold 2.1e-3 absolute at |ref|max≈454
// demands ~1e-6 relative accuracy -> no bf16/MFMA anywhere; CDNA4 has no fp32 MFMA,
// so this is a vector-FP32 (157 TF ceiling) problem).
// Pipeline: QKV GEMM (fp32) -> fused window attention (fp32, in-place over Q slice)
// -> proj GEMM (fp32). Workspace = one qkv buffer; slab-split if ws_size is small.

// ---------------------------------------------------------------------------
// GEMM: C[M x N] = A[M x K (lda)] @ B[K x N row-major] + bias[N]
// 128x128 tile, BK=16, 256 threads, 8x8 per thread.
// LDS sAT[k][m] (transposed at staging, scalar writes) and sB[k][n] (float4
// staging) so the inner loop reads both fragments as float4 -> FMA-bound.
// ---------------------------------------------------------------------------
__global__ __launch_bounds__(256) void gemm_f32(
    const float* __restrict__ A, int lda,
    const float* __restrict__ B,
    const float* __restrict__ bias,
    float* __restrict__ C,
    int M, int N, int K)
{
    __shared__ __attribute__((aligned(16))) float sAT[16 * 128];
    __shared__ __attribute__((aligned(16))) float sB[16 * 128];

    const int tid = threadIdx.x;
    const int tx = tid & 15;          // n-tile 0..15
    const int ty = tid >> 4;          // m-tile 0..15
    const long m0 = (long)blockIdx.y * 128;
    const long n0 = (long)blockIdx.x * 128;

    float acc[8][8];
#pragma unroll
    for (int i = 0; i < 8; ++i)
#pragma unroll
        for (int j = 0; j < 8; ++j) acc[i][j] = 0.f;

    const int ar = tid >> 2;          // A stage row 0..63
    const int ac = (tid & 3) * 4;     // A stage k-col 0,4,8,12

    for (int k0 = 0; k0 < K; k0 += 16) {
        // A tile (128 x 16) -> sAT[k][m]
        float4 a0 = *(const float4*)(A + (m0 + ar) * (long)lda + k0 + ac);
        float4 a1 = *(const float4*)(A + (m0 + ar + 64) * (long)lda + k0 + ac);
#pragma unroll
        for (int j = 0; j < 4; ++j) {
            sAT[(ac + j) * 128 + ar]      = ((const float*)&a0)[j];
            sAT[(ac + j) * 128 + ar + 64] = ((const float*)&a1)[j];
        }
        // B tile (16 x 128) -> sB[k][n], direct float4
#pragma unroll
        for (int h = 0; h < 2; ++h) {
            int idx = tid + h * 256;
            int kk = idx >> 5;
            int c4 = (idx & 31) * 4;
            *(float4*)(sB + kk * 128 + c4) =
                *(const float4*)(B + (long)(k0 + kk) * N + n0 + c4);
        }
        __syncthreads();

#pragma unroll
        for (int kk = 0; kk < 16; ++kk) {
            float4 aF0 = *(const float4*)(sAT + kk * 128 + ty * 8);
            float4 aF1 = *(const float4*)(sAT + kk * 128 + ty * 8 + 4);
            float4 bF0 = *(const float4*)(sB + kk * 128 + tx * 8);
            float4 bF1 = *(const float4*)(sB + kk * 128 + tx * 8 + 4);
            float av[8] = {aF0.x, aF0.y, aF0.z, aF0.w, aF1.x, aF1.y, aF1.z, aF1.w};
            float bv[8] = {bF0.x, bF0.y, bF0.z, bF0.w, bF1.x, bF1.y, bF1.z, bF1.w};
#pragma unroll
            for (int i = 0; i < 8; ++i)
#pragma unroll
                for (int j = 0; j < 8; ++j)
                    acc[i][j] += av[i] * bv[j];
        }
        __syncthreads();
    }

    float bvals[8];
#pragma unroll
    for (int j = 0; j < 8; ++j) bvals[j] = bias[n0 + tx * 8 + j];
#pragma unroll
    for (int i = 0; i < 8; ++i) {
        const long row = m0 + ty * 8 + i;
        float4 o0 = {acc[i][0] + bvals[0], acc[i][1] + bvals[1],
                     acc[i][2] + bvals[2], acc[i][3] + bvals[3]};
        float4 o1 = {acc[i][4] + bvals[4], acc[i][5] + bvals[5],
                     acc[i][6] + bvals[6], acc[i][7] + bvals[7]};
        *(float4*)(C + row * (long)N + n0 + tx * 8)     = o0;
        *(float4*)(C + row * (long)N + n0 + tx * 8 + 4) = o1;
    }
}

// ---------------------------------------------------------------------------
// Fused window attention, fp32. One block per (local window bl, head h).
// qkv rows = bl*128+t (stride 1536); Q at col h*64, K at 512+h*64, V at 1024+h*64.
// S = QK^T*0.125 + bias_table[col-row+127][h] + mask[(b_base+bl)&63][row][col]
// P = softmax_row(S) (normalized in LDS); O = P@V written IN PLACE over Q slice.
// LDS: sQT/sKT 32KB each (transposed, float4 inner reads); sS 128x129 fp32
// (stride 129: PV row-broadcasts land on distinct banks); sQT reused for V.
// ---------------------------------------------------------------------------
__global__ __launch_bounds__(256) void attn_f32(
    const float* __restrict__ qkv,
    float* __restrict__ qkv_out,      // same buffer, non-const alias
    const float* __restrict__ mask,
    const float* __restrict__ bt,
    int b_base)
{
    __shared__ __attribute__((aligned(16))) float sQT[64 * 128]; // later: sV[128][64]
    __shared__ __attribute__((aligned(16))) float sKT[64 * 128];
    __shared__ __attribute__((aligned(16))) float sS[128 * 129];
    __shared__ float sBias[256];

    const int tid = threadIdx.x;
    const int bh = blockIdx.x;
    const int bl = bh >> 3;
    const int h  = bh & 7;
    const int widx = (b_base + bl) & 63;
    const float* base = qkv + (size_t)bl * 128 * 1536 + h * 64;

    // stage Q^T, K^T  (token t -> column, dim d -> row)
    for (int idx = tid; idx < 2048; idx += 256) {
        int t  = idx >> 4;
        int d4 = (idx & 15) * 4;
        float4 q = *(const float4*)(base + (size_t)t * 1536 + d4);
        float4 k = *(const float4*)(base + (size_t)t * 1536 + 512 + d4);
#pragma unroll
        for (int j = 0; j < 4; ++j) {
            sQT[(d4 + j) * 128 + t] = ((const float*)&q)[j];
            sKT[(d4 + j) * 128 + t] = ((const float*)&k)[j];
        }
    }
    if (tid < 255) sBias[tid] = bt[tid * 8 + h];
    __syncthreads();

    const int tx = tid & 15;
    const int ty = tid >> 4;

    // ---- S = Q K^T  (8x8 per thread over 128x128)
    float acc[8][8];
#pragma unroll
    for (int i = 0; i < 8; ++i)
#pragma unroll
        for (int j = 0; j < 8; ++j) acc[i][j] = 0.f;

    for (int kk = 0; kk < 64; ++kk) {
        float4 aF0 = *(const float4*)(sQT + kk * 128 + ty * 8);
        float4 aF1 = *(const float4*)(sQT + kk * 128 + ty * 8 + 4);
        float4 bF0 = *(const float4*)(sKT + kk * 128 + tx * 8);
        float4 bF1 = *(const float4*)(sKT + kk * 128 + tx * 8 + 4);
        float av[8] = {aF0.x, aF0.y, aF0.z, aF0.w, aF1.x, aF1.y, aF1.z, aF1.w};
        float bv[8] = {bF0.x, bF0.y, bF0.z, bF0.w, bF1.x, bF1.y, bF1.z, bF1.w};
#pragma unroll
        for (int i = 0; i < 8; ++i)
#pragma unroll
            for (int j = 0; j < 8; ++j)
                acc[i][j] += av[i] * bv[j];
    }

    // scale + rel-pos bias + mask, write S to LDS (stride 129)
    const float* maskp = mask + (size_t)widx * 16384;
#pragma unroll
    for (int i = 0; i < 8; ++i) {
        const int row = ty * 8 + i;
#pragma unroll
        for (int j = 0; j < 8; ++j) {
            const int col = tx * 8 + j;
            sS[row * 129 + col] = acc[i][j] * 0.125f + sBias[col - row + 127]
                                + maskp[row * 128 + col];
        }
    }
    __syncthreads();

    // ---- softmax: thread pair (tid, tid^1) owns one row (halves of 64)
    {
        const int row = tid >> 1;
        const int hc  = (tid & 1) * 64;
        float* rp = sS + row * 129 + hc;
        float mx = -3.4e38f;
        for (int c = 0; c < 64; ++c) mx = fmaxf(mx, rp[c]);
        mx = fmaxf(mx, __shfl_xor(mx, 1));
        float sum = 0.f;
        for (int c = 0; c < 64; ++c) {
            float e = __expf(rp[c] - mx);
            rp[c] = e;
            sum += e;
        }
        sum += __shfl_xor(sum, 1);
        const float rl = 1.0f / sum;
        for (int c = 0; c < 64; ++c) rp[c] *= rl;
    }

    // stage V into the dead sQT region: sV[t][d] (natural layout, float4)
    float* sV = sQT;
    for (int idx = tid; idx < 2048; idx += 256) {
        int t  = idx >> 4;
        int d4 = (idx & 15) * 4;
        *(float4*)(sV + t * 64 + d4) =
            *(const float4*)(base + (size_t)t * 1536 + 1024 + d4);
    }
    __syncthreads();

    // ---- O = P V : 8 rows x 4 cols per thread (128 x 64 output)
    float o[8][4];
#pragma unroll
    for (int i = 0; i < 8; ++i)
#pragma unroll
        for (int j = 0; j < 4; ++j) o[i][j] = 0.f;

    for (int k = 0; k < 128; ++k) {
        float4 bF = *(const float4*)(sV + k * 64 + tx * 4);
        float bv[4] = {bF.x, bF.y, bF.z, bF.w};
#pragma unroll
        for (int i = 0; i < 8; ++i) {
            const float a = sS[(ty * 8 + i) * 129 + k];   // 16-lane broadcast
#pragma unroll
            for (int j = 0; j < 4; ++j) o[i][j] += a * bv[j];
        }
    }

    // in-place write over the Q slice of this (bl, h)
#pragma unroll
    for (int i = 0; i < 8; ++i) {
        const int row = ty * 8 + i;
        float4 ov = {o[i][0], o[i][1], o[i][2], o[i][3]};
        *(float4*)(qkv_out + (size_t)(bl * 128 + row) * 1536 + h * 64 + tx * 4) = ov;
    }
}

// ---------------------------------------------------------------------------
extern "C" void kernel_launch(void* const* d_in, const int* in_sizes, int n_in,
                              void* d_out, int out_size, void* d_ws, size_t ws_size,
                              hipStream_t stream) {
    const float* x      = (const float*)d_in[0];
    const float* mask   = (const float*)d_in[1];
    const float* w_qkv  = (const float*)d_in[2];   // 512 x 1536 row-major = B for gemm1
    const float* b_qkv  = (const float*)d_in[3];
    const float* w_proj = (const float*)d_in[4];   // 512 x 512 row-major = B for gemm2
    const float* b_proj = (const float*)d_in[5];
    const float* btab   = (const float*)d_in[6];
    float* out = (float*)d_out;

    float* qkv_ws = (float*)d_ws;

    // Slab over windows if ws_size can't hold the full qkv (1024*128*1536*4 = 805 MB)
    int nslab = 1;
    while (nslab < 32 && (size_t)(131072 / nslab) * 1536 * 4 > ws_size) nslab <<= 1;
    const int Ms  = 131072 / nslab;   // rows per slab
    const int Wsl = 1024 / nslab;     // windows per slab

    for (int s = 0; s < nslab; ++s) {
        const float* xs = x + (size_t)s * Ms * 512;
        float* outs = out + (size_t)s * Ms * 512;

        gemm_f32<<<dim3(12, Ms / 128), 256, 0, stream>>>(
            xs, 512, w_qkv, b_qkv, qkv_ws, Ms, 1536, 512);

        attn_f32<<<Wsl * 8, 256, 0, stream>>>(
            qkv_ws, qkv_ws, mask, btab, s * Wsl);

        gemm_f32<<<dim3(4, Ms / 128), 256, 0, stream>>>(
            qkv_ws, 1536, w_proj, b_proj, outs, Ms, 512, 512);
    }
}